// Round 1
// baseline (72.839 us; speedup 1.0000x reference)
//
#include <hip/hip_runtime.h>
#include <hip/hip_bf16.h>
#include <math.h>

#define NUM_EMB 8192
#define NTOK    32768                 // B*L = 8*4096
#define SB      32                    // 1 MFMA = 32 embeddings
#define NSLICE  8                     // emb-slices, one per wave
#define SBSL    (NUM_EMB / SB / NSLICE)   // 32 sbs per wave
#define TPB     512                   // 8 waves
#define TOKPB   64                    // tokens per block
#define NB      (NTOK / TOKPB)        // 512 blocks = 2/CU

typedef __attribute__((ext_vector_type(8)))  short short8;   // 8 bf16
typedef __attribute__((ext_vector_type(16))) float f32x16;   // 32x32 C/D

__device__ __forceinline__ short8 pack2(__hip_bfloat162 a, __hip_bfloat162 b,
                                        __hip_bfloat162 c, __hip_bfloat162 d) {
    union { short8 s; __hip_bfloat162 h[4]; } u;
    u.h[0] = a; u.h[1] = b; u.h[2] = c; u.h[3] = d;
    return u.s;
}

// fp32 -> bf16 hi + bf16 residual lo (hi+lo ~ 2^-17 rel; proven R7-R11)
__device__ __forceinline__ void split4(float4 v,
        __hip_bfloat162& hxy, __hip_bfloat162& hzw,
        __hip_bfloat162& lxy, __hip_bfloat162& lzw) {
    hxy = __float22bfloat162_rn(make_float2(v.x, v.y));
    hzw = __float22bfloat162_rn(make_float2(v.z, v.w));
    lxy = __float22bfloat162_rn(make_float2(v.x - __low2float(hxy),
                                            v.y - __high2float(hxy)));
    lzw = __float22bfloat162_rn(make_float2(v.z - __low2float(hzw),
                                            v.w - __high2float(hzw)));
}

// fmaxf(fmaxf(a,b),c) fuses to v_max3_f32: 16 values in 8 ops
__device__ __forceinline__ float tree16(const f32x16& d) {
    float a = fmaxf(fmaxf(d[0],  d[1]),  d[2]);
    float b = fmaxf(fmaxf(d[3],  d[4]),  d[5]);
    float c = fmaxf(fmaxf(d[6],  d[7]),  d[8]);
    float e = fmaxf(fmaxf(d[9],  d[10]), d[11]);
    float f = fmaxf(fmaxf(d[12], d[13]), d[14]);
    float m = fmaxf(fmaxf(a, b), c);
    float n = fmaxf(fmaxf(e, f), d[15]);
    return fmaxf(m, n);
}

// LDS-free restructure. Rationale: in the 64-token/wave decomposition each
// staged emb fragment was consumed by exactly one wave (reuse=1), so the
// global->LDS->reg round-trip plus its 3 block-wide barriers bought nothing.
// Each wave owns token-groups {t0,t1} x emb-slice sl (1024 embs = 32 sbs) and
// streams A-fragments straight from global (L2-resident 128 KB table,
// broadcast-coalesced: 32 lanes x 16 B, halves duplicate). Hot loop:
// global_load_dwordx4 -> split4/pack2 -> 2 MFMAs -> max3 trees -> sb select.
// One barrier total (keybuf combine). 2 blocks/CU overlap tails.
__global__ __launch_bounds__(TPB, 4) void vq_nolds(
    const float4* __restrict__ x,
    const float4* __restrict__ emb,
    float* __restrict__ out) {

    __shared__ unsigned keybuf[NSLICE * TOKPB];  // 2 KB

    const int lane = threadIdx.x & 63;
    const int col  = lane & 31;
    const int half = lane >> 5;
    const int sl   = threadIdx.x >> 6;        // wave = emb-slice 0..7
    const int t0   = blockIdx.x * TOKPB + col;
    const int t1   = t0 + 32;

    // ---- two B fragments (this lane's tokens), fixed for whole kernel ----
    // half 0 supplies K 0..7 (x_hi dup), half 1 K 8..15 (x_lo dup):
    // summed with A=[e_hi,e_lo] rows gives (e_hi+e_lo)(x_hi+x_lo) ~ exact fp32.
    __hip_bfloat162 hxy, hzw, lxy, lzw;
    const float4 xv0 = x[t0];
    split4(xv0, hxy, hzw, lxy, lzw);
    const short8 bf0 = half ? pack2(lxy, lzw, lxy, lzw)
                            : pack2(hxy, hzw, hxy, hzw);
    const float4 xv1 = x[t1];
    split4(xv1, hxy, hzw, lxy, lzw);
    const short8 bf1 = half ? pack2(lxy, lzw, lxy, lzw)
                            : pack2(hxy, hzw, hxy, hzw);

    const f32x16 zero = {0,0,0,0,0,0,0,0,0,0,0,0,0,0,0,0};
    float best0 = -INFINITY, best1 = -INFINITY;
    int   bsb0 = 0, bsb1 = 0;

    // ---- this wave's slice: 32 sbs, load -> convert -> 2 MFMAs ----
    const float4* ep = emb + (sl * SBSL) * SB + col;
    #pragma unroll 4
    for (int i = 0; i < SBSL; ++i) {
        float4 ev = ep[i * SB];               // emb[(sl*32+i)*32 + col]
        __hip_bfloat162 ehxy, ehzw, elxy, elzw;
        split4(ev, ehxy, ehzw, elxy, elzw);
        short8 af = pack2(ehxy, ehzw, elxy, elzw);   // [e_hi(4), e_lo(4)]
        f32x16 d0 = __builtin_amdgcn_mfma_f32_32x32x16_bf16(af, bf0, zero, 0, 0, 0);
        f32x16 d1 = __builtin_amdgcn_mfma_f32_32x32x16_bf16(af, bf1, zero, 0, 0, 0);
        float m0 = tree16(d0);
        float m1 = tree16(d1);
        const int gsb = sl * SBSL + i;
        bool c0 = m0 > best0;                 // ascending: earliest sb wins
        bool c1 = m1 > best1;
        bsb0  = c0 ? gsb : bsb0;  best0 = c0 ? m0 : best0;
        bsb1  = c1 ? gsb : bsb1;  best1 = c1 ? m1 : best1;
    }

    // ---- pack sortable keys; combine halves by umax; publish per slice ----
    unsigned u0 = __float_as_uint(best0);
    unsigned s0 = ((int)u0 < 0) ? ~u0 : (u0 | 0x80000000u);
    unsigned k0 = (s0 & ~255u) | (255u - (unsigned)bsb0);
    unsigned u1 = __float_as_uint(best1);
    unsigned s1 = ((int)u1 < 0) ? ~u1 : (u1 | 0x80000000u);
    unsigned k1 = (s1 & ~255u) | (255u - (unsigned)bsb1);

    unsigned o0 = (unsigned)__shfl_xor((int)k0, 32, 64);
    k0 = (o0 > k0) ? o0 : k0;
    unsigned o1 = (unsigned)__shfl_xor((int)k1, 32, 64);
    k1 = (o1 > k1) ? o1 : k1;

    if (half == 0) {
        keybuf[sl * TOKPB + col]      = k0;
        keybuf[sl * TOKPB + 32 + col] = k1;
    }
    __syncthreads();

    // ---- tail: wave 0 owns one token each; exact fp32 re-scan of best sb ----
    if (threadIdx.x < TOKPB) {
        const int t = threadIdx.x;
        unsigned k = keybuf[t];
        #pragma unroll
        for (int c = 1; c < NSLICE; ++c) {
            unsigned o = keybuf[c * TOKPB + t];
            k = (o > k) ? o : k;
        }
        const int sbid = 255 - (int)(k & 255u);
        const float4* eb = emb + sbid * SB;
        const float4 xt = x[blockIdx.x * TOKPB + t];

        float bd = -INFINITY;
        float4 e = xt;
        #pragma unroll 4
        for (int j = 0; j < SB; ++j) {        // ascending: first-max wins
            float4 c4 = eb[j];
            float dj = fmaf(xt.w, c4.w, fmaf(xt.z, c4.z,
                        fmaf(xt.y, c4.y, xt.x * c4.x)));
            bool c = dj > bd;
            bd = c ? dj : bd;
            e.x = c ? c4.x : e.x;  e.y = c ? c4.y : e.y;
            e.z = c ? c4.z : e.z;  e.w = c ? c4.w : e.w;
        }
        float s = fabsf(xt.x - e.x) + fabsf(xt.y - e.y)
                + fabsf(xt.z - e.z) + fabsf(xt.w - e.w);

        // wave-0-only reduce -> one atomicAdd per block
        #pragma unroll
        for (int off = 32; off > 0; off >>= 1)
            s += __shfl_down(s, off, 64);
        if (t == 0)
            atomicAdd(out, s * (2.0f / (float)(NTOK * 4)));
    }
}

extern "C" void kernel_launch(void* const* d_in, const int* in_sizes, int n_in,
                              void* d_out, int out_size, void* d_ws, size_t ws_size,
                              hipStream_t stream) {
    const float4* x4  = (const float4*)d_in[0];   // [8,4096,4] fp32
    const float4* emb = (const float4*)d_in[1];   // [8192,4]   fp32
    float* out = (float*)d_out;

    vq_nolds<<<NB, TPB, 0, stream>>>(x4, emb, out);
}

// Round 2
// 72.560 us; speedup vs baseline: 1.0038x; 1.0038x over previous
//
#include <hip/hip_runtime.h>
#include <hip/hip_bf16.h>
#include <math.h>

#define NUM_EMB 8192
#define NTOK    32768                 // B*L = 8*4096
#define SB      32                    // 1 MFMA = 32 embeddings
#define NSLICE  8                     // emb-slices, one per wave
#define SBSL    (NUM_EMB / SB / NSLICE)   // 32 sbs per wave
#define TPB     512                   // 8 waves
#define TOKPB   64                    // tokens per block
#define NB      (NTOK / TOKPB)        // 512 blocks = 2/CU

typedef __attribute__((ext_vector_type(8)))  short short8;   // 8 bf16
typedef __attribute__((ext_vector_type(16))) float f32x16;   // 32x32 C/D

__device__ __forceinline__ short8 pack2(__hip_bfloat162 a, __hip_bfloat162 b,
                                        __hip_bfloat162 c, __hip_bfloat162 d) {
    union { short8 s; __hip_bfloat162 h[4]; } u;
    u.h[0] = a; u.h[1] = b; u.h[2] = c; u.h[3] = d;
    return u.s;
}

// fp32 -> bf16 hi + bf16 residual lo (hi+lo ~ 2^-17 rel; proven R7-R11)
__device__ __forceinline__ void split4(float4 v,
        __hip_bfloat162& hxy, __hip_bfloat162& hzw,
        __hip_bfloat162& lxy, __hip_bfloat162& lzw) {
    hxy = __float22bfloat162_rn(make_float2(v.x, v.y));
    hzw = __float22bfloat162_rn(make_float2(v.z, v.w));
    lxy = __float22bfloat162_rn(make_float2(v.x - __low2float(hxy),
                                            v.y - __high2float(hxy)));
    lzw = __float22bfloat162_rn(make_float2(v.z - __low2float(hzw),
                                            v.w - __high2float(hzw)));
}

// fmaxf(fmaxf(a,b),c) fuses to v_max3_f32: 16 values in 8 ops
__device__ __forceinline__ float tree16(const f32x16& d) {
    float a = fmaxf(fmaxf(d[0],  d[1]),  d[2]);
    float b = fmaxf(fmaxf(d[3],  d[4]),  d[5]);
    float c = fmaxf(fmaxf(d[6],  d[7]),  d[8]);
    float e = fmaxf(fmaxf(d[9],  d[10]), d[11]);
    float f = fmaxf(fmaxf(d[12], d[13]), d[14]);
    float m = fmaxf(fmaxf(a, b), c);
    float n = fmaxf(fmaxf(e, f), d[15]);
    return fmaxf(m, n);
}

// R2 pre-kernel: convert the 8192-entry table ONCE into packed bf16 hi/lo
// A-fragments in the workspace (128 KB of the 256 MiB ws). Removes per-block
// re-conversion (512 blocks x 8192 embs -> 1 x 8192) and, critically, the
// 4-step dependent split4 chain between load-return and MFMA-issue in the
// hot loop (H_slow latency discriminator).
__global__ __launch_bounds__(256) void emb_pack(
    const float4* __restrict__ emb, short8* __restrict__ tbl) {
    const int i = blockIdx.x * 256 + threadIdx.x;   // 0..8191
    __hip_bfloat162 hxy, hzw, lxy, lzw;
    split4(emb[i], hxy, hzw, lxy, lzw);
    tbl[i] = pack2(hxy, hzw, lxy, lzw);             // [e_hi(4), e_lo(4)]
}

// Main kernel (R1 structure): wave = emb-slice, 64 tokens/block, no LDS
// staging, one barrier (keybuf combine). Hot loop is now
// global_load_dwordx4 -> 2 MFMAs -> max3 trees -> sb select (~26 VALU/iter).
__global__ __launch_bounds__(TPB, 4) void vq_main(
    const float4* __restrict__ x,
    const short8* __restrict__ tbl,
    const float4* __restrict__ emb,
    float* __restrict__ out) {

    __shared__ unsigned keybuf[NSLICE * TOKPB];  // 2 KB

    const int lane = threadIdx.x & 63;
    const int col  = lane & 31;
    const int half = lane >> 5;
    const int sl   = threadIdx.x >> 6;        // wave = emb-slice 0..7
    const int t0   = blockIdx.x * TOKPB + col;
    const int t1   = t0 + 32;

    // ---- two B fragments (this lane's tokens), fixed for whole kernel ----
    // half 0 supplies K 0..7 (x_hi dup), half 1 K 8..15 (x_lo dup):
    // summed with A=[e_hi,e_lo] rows gives (e_hi+e_lo)(x_hi+x_lo) ~ exact fp32.
    __hip_bfloat162 hxy, hzw, lxy, lzw;
    const float4 xv0 = x[t0];
    split4(xv0, hxy, hzw, lxy, lzw);
    const short8 bf0 = half ? pack2(lxy, lzw, lxy, lzw)
                            : pack2(hxy, hzw, hxy, hzw);
    const float4 xv1 = x[t1];
    split4(xv1, hxy, hzw, lxy, lzw);
    const short8 bf1 = half ? pack2(lxy, lzw, lxy, lzw)
                            : pack2(hxy, hzw, hxy, hzw);

    const f32x16 zero = {0,0,0,0,0,0,0,0,0,0,0,0,0,0,0,0};
    float best0 = -INFINITY, best1 = -INFINITY;
    int   bsb0 = 0, bsb1 = 0;

    // ---- this wave's slice: 32 sbs, pre-packed load -> 2 MFMAs ----
    const short8* tp = tbl + (sl * SBSL) * SB + col;
    #pragma unroll 4
    for (int i = 0; i < SBSL; ++i) {
        short8 af = tp[i * SB];               // tbl[(sl*32+i)*32 + col]
        f32x16 d0 = __builtin_amdgcn_mfma_f32_32x32x16_bf16(af, bf0, zero, 0, 0, 0);
        f32x16 d1 = __builtin_amdgcn_mfma_f32_32x32x16_bf16(af, bf1, zero, 0, 0, 0);
        float m0 = tree16(d0);
        float m1 = tree16(d1);
        const int gsb = sl * SBSL + i;
        bool c0 = m0 > best0;                 // ascending: earliest sb wins
        bool c1 = m1 > best1;
        bsb0  = c0 ? gsb : bsb0;  best0 = c0 ? m0 : best0;
        bsb1  = c1 ? gsb : bsb1;  best1 = c1 ? m1 : best1;
    }

    // ---- pack sortable keys; combine halves by umax; publish per slice ----
    unsigned u0 = __float_as_uint(best0);
    unsigned s0 = ((int)u0 < 0) ? ~u0 : (u0 | 0x80000000u);
    unsigned k0 = (s0 & ~255u) | (255u - (unsigned)bsb0);
    unsigned u1 = __float_as_uint(best1);
    unsigned s1 = ((int)u1 < 0) ? ~u1 : (u1 | 0x80000000u);
    unsigned k1 = (s1 & ~255u) | (255u - (unsigned)bsb1);

    unsigned o0 = (unsigned)__shfl_xor((int)k0, 32, 64);
    k0 = (o0 > k0) ? o0 : k0;
    unsigned o1 = (unsigned)__shfl_xor((int)k1, 32, 64);
    k1 = (o1 > k1) ? o1 : k1;

    if (half == 0) {
        keybuf[sl * TOKPB + col]      = k0;
        keybuf[sl * TOKPB + 32 + col] = k1;
    }
    __syncthreads();

    // ---- tail: wave 0 owns one token each; exact fp32 re-scan of best sb ----
    if (threadIdx.x < TOKPB) {
        const int t = threadIdx.x;
        unsigned k = keybuf[t];
        #pragma unroll
        for (int c = 1; c < NSLICE; ++c) {
            unsigned o = keybuf[c * TOKPB + t];
            k = (o > k) ? o : k;
        }
        const int sbid = 255 - (int)(k & 255u);
        const float4* eb = emb + sbid * SB;
        const float4 xt = x[blockIdx.x * TOKPB + t];

        float bd = -INFINITY;
        float4 e = xt;
        #pragma unroll 4
        for (int j = 0; j < SB; ++j) {        // ascending: first-max wins
            float4 c4 = eb[j];
            float dj = fmaf(xt.w, c4.w, fmaf(xt.z, c4.z,
                        fmaf(xt.y, c4.y, xt.x * c4.x)));
            bool c = dj > bd;
            bd = c ? dj : bd;
            e.x = c ? c4.x : e.x;  e.y = c ? c4.y : e.y;
            e.z = c ? c4.z : e.z;  e.w = c ? c4.w : e.w;
        }
        float s = fabsf(xt.x - e.x) + fabsf(xt.y - e.y)
                + fabsf(xt.z - e.z) + fabsf(xt.w - e.w);

        // wave-0-only reduce -> one atomicAdd per block
        #pragma unroll
        for (int off = 32; off > 0; off >>= 1)
            s += __shfl_down(s, off, 64);
        if (t == 0)
            atomicAdd(out, s * (2.0f / (float)(NTOK * 4)));
    }
}

extern "C" void kernel_launch(void* const* d_in, const int* in_sizes, int n_in,
                              void* d_out, int out_size, void* d_ws, size_t ws_size,
                              hipStream_t stream) {
    const float4* x4  = (const float4*)d_in[0];   // [8,4096,4] fp32
    const float4* emb = (const float4*)d_in[1];   // [8192,4]   fp32
    float* out = (float*)d_out;
    short8* tbl = (short8*)d_ws;                  // 128 KB of the 256 MiB ws

    emb_pack<<<NUM_EMB / 256, 256, 0, stream>>>(emb, tbl);
    vq_main<<<NB, TPB, 0, stream>>>(x4, tbl, emb, out);
}